// Round 8
// baseline (16.909 us; speedup 1.0000x reference)
//
#include <hip/hip_runtime.h>
#include <math.h>

// HippoSSKernel (S4 SSKernelDiag forward, ZOH): K[h,l] = 2*Re(sum_n Cw[h,n]*exp(dtA[h,n]*l))
// H=1024, N=64, CH=1, L=2048.
//
// R8: ONE WAVE PER HEAD (TPH=64, LPT=32, q=b^64) -> total waves 1024 (half of
// R7) -> total LDS traffic 3x lower. Table stores z = Cw2*b^lane PRE-MULTIPLIED
// (hw is now w2-independent), split into x/y planes so prologue writes are a
// perfect bank permutation (conflict-free) and main-loop reads are 2x b64.
// Per n-pair: 3 LDS reads + 97 pk-inst for 64 terms (packed f32, VOP3P).
// 4 heads/block, LDS ~134 KB -> 1 block/CU, 256 blocks = 256 CUs.

#define HH   1024
#define NN   64
#define LLEN 2048
#define TPB  256
#define HPB  4                 // heads per block (1 wave each)
#define LPT  32                // terms per thread (l = lane + 64*j)
#define NP   (NN / 2)          // 32 n-pairs

typedef float v2f __attribute__((ext_vector_type(2)));
typedef float v4f __attribute__((ext_vector_type(4)));

__device__ __forceinline__ float2 cmul(float2 a, float2 b) {
    return make_float2(fmaf(a.x, b.x, -(a.y * b.y)),
                       fmaf(a.x, b.y,   a.y * b.x));
}

__device__ __forceinline__ v2f vfma(v2f a, v2f b, v2f c) {
    return __builtin_elementwise_fma(a, b, c);
}

__global__ __launch_bounds__(TPB, 1) void sskernel_diag(
    const float* __restrict__ log_dt,      // (H,)
    const float* __restrict__ log_w_real,  // (H,N)
    const float* __restrict__ w_imag,      // (H,N)
    const float* __restrict__ C_re,        // (1,H,N)
    const float* __restrict__ C_im,        // (1,H,N)
    float* __restrict__ out)               // (1,H,L)
{
    // x/y planes: [s][p][j] = {v_even_n, v_odd_n}; row pad 65 -> write banks
    // (lane + 2j) mod 32: 2-way aliasing = free. Read [s][pp][lane]: consecutive.
    __shared__ v2f s_Tx[HPB][NP][NN + 1];   // zx = Re(Cw2 * b^j)   (66560 B)
    __shared__ v2f s_Ty[HPB][NP][NN + 1];   // zy = Im(Cw2 * b^j)   (66560 B)
    __shared__ v4f s_Q[HPB][NP];            // {qx_e, qx_o, qy_e, qy_o} (2048 B)

    const int t    = threadIdx.x;
    const int s    = t >> 6;               // head within block (0..3) == wave
    const int lane = t & 63;
    const int h    = blockIdx.x * HPB + s;

    // ---- Prologue: thread (h, lane) computes n = lane's parameters ----
    const int n   = lane;
    const int p   = n >> 1;
    const int sl  = n & 1;                 // slot within pair
    const int idx = h * NN + n;
    const float dtv = expf(log_dt[h]);
    const float wr  = -expf(log_w_real[idx]);
    const float wi  = w_imag[idx];
    const float dar = wr * dtv;
    const float dai = wi * dtv;

    const float em = expf(dar);
    float sv, cv;
    sincosf(dai, &sv, &cv);
    const float2 b = make_float2(em * cv, em * sv);     // exp(dtA)

    // Cw2 = 2 * C * (b - 1) / w   (final factor of 2 folded in)
    const float numr = b.x - 1.0f;
    const float numi = b.y;
    const float inv  = 2.0f / (wr * wr + wi * wi);
    const float tr = (numr * wr + numi * wi) * inv;
    const float ti = (numi * wr - numr * wi) * inv;
    const float cr = C_re[idx];
    const float ci = C_im[idx];
    const float2 Cw2 = make_float2(cr * tr - ci * ti, cr * ti + ci * tr);

    // squaring chain to q = b^64
    const float2 q1 = cmul(b,  b);
    const float2 q2 = cmul(q1, q1);
    const float2 q3 = cmul(q2, q2);
    const float2 q4 = cmul(q3, q3);   // b^16
    const float2 q5 = cmul(q4, q4);   // b^32
    const float2 q6 = cmul(q5, q5);   // q = b^64

    {   // packed per-pair constants
        float* f = (float*)&s_Q[s][p];
        f[sl] = q6.x; f[2 + sl] = q6.y;
    }

    // fill T'[p][j] = Cw2 * b^j, two half-chains (j and j+32) to halve latency
    float2 e  = Cw2;
    float2 e2 = cmul(Cw2, q5);        // Cw2 * b^32
#pragma unroll
    for (int j = 0; j < 32; ++j) {
        float* fx  = (float*)&s_Tx[s][p][j];
        float* fy  = (float*)&s_Ty[s][p][j];
        float* fx2 = (float*)&s_Tx[s][p][j + 32];
        float* fy2 = (float*)&s_Ty[s][p][j + 32];
        fx[sl]  = e.x;   fy[sl]  = e.y;
        fx2[sl] = e2.x;  fy2[sl] = e2.y;
        e  = cmul(e,  b);
        e2 = cmul(e2, b);
    }
    __syncthreads();

    // ---- Main loop: 3 LDS reads + 97 pk-inst per n-pair (64 terms) ----
    v2f acc[LPT] = {};

#pragma unroll 8
    for (int pp = 0; pp < NP; ++pp) {
        const v2f Tx = s_Tx[s][pp][lane];   // {zx_e, zx_o} = Re(Cw2*b^lane)
        const v2f Ty = s_Ty[s][pp][lane];   // {zy_e, zy_o}
        const v4f Q  = s_Q[s][pp];          // uniform -> broadcast

        const v2f qx = {Q.x, Q.y}, qy = {Q.z, Q.w};
        const v2f an = qx + qx;                       // 2 Re(q)
        const v2f m  = vfma(qx, qx, qy * qy);         // |q|^2
        v2f u0 = Tx;                                  // Re(z)        (j=0)
        v2f u1 = vfma(Tx, qx, -(Ty * qy));            // Re(z*q)      (j=1)
        acc[0] += u0;
        acc[1] += u1;
#pragma unroll
        for (int j = 2; j < LPT; ++j) {
            const v2f u = vfma(an, u1, -(m * u0));    // packed Chebyshev step
            acc[j] += u;
            u0 = u1;
            u1 = u;
        }
    }

    // ---- Epilogue: coalesced stores (2x folded into Cw2) ----
    float* o = out + (size_t)h * LLEN;
#pragma unroll
    for (int j = 0; j < LPT; ++j)
        o[lane + j * 64] = acc[j].x + acc[j].y;
}

extern "C" void kernel_launch(void* const* d_in, const int* in_sizes, int n_in,
                              void* d_out, int out_size, void* d_ws, size_t ws_size,
                              hipStream_t stream) {
    const float* log_dt     = (const float*)d_in[0];
    const float* log_w_real = (const float*)d_in[1];
    const float* w_imag     = (const float*)d_in[2];
    const float* C_re       = (const float*)d_in[3];
    const float* C_im       = (const float*)d_in[4];
    float* out = (float*)d_out;

    sskernel_diag<<<HH / HPB, TPB, 0, stream>>>(log_dt, log_w_real, w_imag, C_re, C_im, out);
}